// Round 11
// baseline (274.224 us; speedup 1.0000x reference)
//
#include <hip/hip_runtime.h>

// NeighbourCovariance: per vertex v, gather K=40 neighbors, weight features by
// exp(-10*distsq), compute per-feature weighted mean (C=3) and covariance (3x3).
// Output layout per vertex: [cov (F*9)] ++ [means (F*3)] = 384 floats.
//
// R13: LDS-pipe attack. Corrected pipe accounting: phase-2 VALU ~26 us/CU, but
// phase-2 LDS ~58 us/CU (2M ds_read_b128 + 2M ds_read_b32, one LDS unit/CU) --
// LDS is THE dominant pipe; that's why VALU cuts (R5/R12) were neutral.
// Fix: lane = (vertex, feature-PAIR). 16 lanes x f16x2 cover a full 32-f row,
// so a wave serves 4 vertices: the per-k broadcast b128(wxyz)+b32(joff) now
// amortizes over 4 vertices -> phase-2 LDS 58 -> 29 us. Gather instrs halve
// (4 rows/instr), same 4M requests. s_wxyz padded stride 41 so the 4 broadcast
// groups hit disjoint bank quads (unpadded stride 640B = all groups on bank 0).
// Output staged in two 8-vertex chunks to keep LDS at 25344 B -> 6 blocks/CU.
//
//  Pass 0:  cvt features f32 -> fp16 [V][32] in d_ws (~6 us).
//  Phase 1: 640 (v,k) pairs; NT stream loads, one exp, coord gather ->
//           (w,x,y,z) padded + joff in LDS.
//  Phase 2: lane=(v, fpair); 40 x {b128+b32 broadcast + 4B f16x2 gather +
//           ~30 VALU for two feature bodies}.
//  Phase 3: two chunks of 8 vertices: stage in LDS -> coalesced 16B NT stores.
//
// f32 fallback (R4 structure, 95 us known-good) if ws too small.

constexpr int K = 40;
constexpr int C = 3;
constexpr int F = 32;
constexpr float EPS = 1e-3f;
constexpr float DIST_SCALE = 10.0f;
constexpr int OUT_PER_V = F * C * C + F * C;  // 384 floats = 96 float4
constexpr int VPB = 16;                       // vertices per 256-thread block
constexpr int PAIRS = VPB * K;                // 640
constexpr int WSTRIDE = K + 1;                // padded float4 stride (bank fix)
constexpr int OUT_F4 = 768;                   // stage: 8 vertices * 96 float4

typedef float    floatx4 __attribute__((ext_vector_type(4)));  // nt-store ok
typedef float    f32x8   __attribute__((ext_vector_type(8)));
typedef _Float16 f16x8   __attribute__((ext_vector_type(8)));
typedef _Float16 f16x2   __attribute__((ext_vector_type(2)));

// ---- Pass 0: features f32 -> fp16 (12.8 MB -> 6.4 MB), 8 elems/thread ----
__global__ __launch_bounds__(256) void cvt_kernel(
    const float* __restrict__ in, _Float16* __restrict__ out16, int n8)
{
    const int i = blockIdx.x * 256 + threadIdx.x;
    if (i < n8) {
        const f32x8 v = __builtin_nontemporal_load((const f32x8*)in + i);
        const f16x8 o = __builtin_convertvector(v, f16x8);
        *((f16x8*)out16 + i) = o;   // cached store: re-read by main kernel
    }
}

// ---- Main kernel: fp16 gather, 2 features per lane, 4 vertices per wave ----
__global__ __launch_bounds__(256) void neighcov_f16x2(
    const float* __restrict__ coords,      // V x 3
    const float* __restrict__ distsq,      // V x K
    const _Float16* __restrict__ features, // V x F fp16
    const int*   __restrict__ nidx,        // V x K
    float* __restrict__ out,               // V x 384
    int V)
{
    __shared__ float4  s_wxyz[VPB * WSTRIDE]; // (w,x,y,z), padded      10496 B
    __shared__ int     s_joff[PAIRS];         // j*F element offset      2560 B
    __shared__ floatx4 s_out4[OUT_F4];        // 8-vertex output stage  12288 B

    const int tid   = threadIdx.x;
    const int vbase = blockIdx.x * VPB;
    const long long total_pairs = (long long)V * K;

    // ---- Phase 1: stage weights/coords, 640 pairs (streams read once) ----
    for (int p = tid; p < PAIRS; p += 256) {
        const long long gp = (long long)vbase * K + p;
        int idx = -1;
        float d = 0.f;
        if (gp < total_pairs) {
            idx = __builtin_nontemporal_load(nidx + gp);    // coalesced, single-use
            d   = __builtin_nontemporal_load(distsq + gp);  // coalesced, single-use
        }
        const bool valid = (idx >= 0);
        const int j = valid ? idx : 0;
        const float w = valid ? __expf(-DIST_SCALE * d) : 0.f;  // w==0 = invalid
        const float x = coords[(size_t)j * 3 + 0];
        const float y = coords[(size_t)j * 3 + 1];
        const float z = coords[(size_t)j * 3 + 2];
        const int vl = p / K, kk = p - vl * K;
        s_wxyz[vl * WSTRIDE + kk] = make_float4(w, x, y, z);
        s_joff[p] = j * F;
    }
    __syncthreads();

    // ---- Phase 2: lane = (vertex, feature-pair) ----
    const int fl   = tid & 15;   // feature-pair slot: covers f = 2fl, 2fl+1
    const int vloc = tid >> 4;   // 0..15 (4 vertices per wave)
    const float4* wp = &s_wxyz[vloc * WSTRIDE];
    const int*    jp = &s_joff[vloc * K];

    float wsA = 0.f, m0A = 0.f, m1A = 0.f, m2A = 0.f;
    float s00A = 0.f, s01A = 0.f, s02A = 0.f, s11A = 0.f, s12A = 0.f, s22A = 0.f;
    float wsB = 0.f, m0B = 0.f, m1B = 0.f, m2B = 0.f;
    float s00B = 0.f, s01B = 0.f, s02B = 0.f, s11B = 0.f, s12B = 0.f, s22B = 0.f;

    #pragma unroll 8
    for (int k = 0; k < K; ++k) {
        const float4 q = wp[k];            // b128 broadcast, 4 groups on disjoint quads
        const int jo   = jp[k];            // b32 broadcast, 4 distinct banks
        const f16x2 f2 = *(const f16x2*)(features + jo + 2 * fl);  // 64B/row x 4 rows
        const float x = q.y, y = q.z, z = q.w;
        const float ftA = (float)f2.x, ftB = (float)f2.y;
        const float fwA = q.x * ftA,   fwB = q.x * ftB;   // w==0 = invalid
        const float fxA = fwA * x, fyA = fwA * y, fzA = fwA * z;
        const float fxB = fwB * x, fyB = fwB * y, fzB = fwB * z;
        wsA += fwA;  m0A += fxA;  m1A += fyA;  m2A += fzA;
        s00A += fxA * x; s01A += fxA * y; s02A += fxA * z;
        s11A += fyA * y; s12A += fyA * z; s22A += fzA * z;
        wsB += fwB;  m0B += fxB;  m1B += fyB;  m2B += fzB;
        s00B += fxB * x; s01B += fxB * y; s02B += fxB * z;
        s11B += fyB * y; s12B += fyB * z; s22B += fzB * z;
    }

    // Epilogue for both features of this lane.
    const float invA = 1.f / (wsA + EPS);
    const float muA0 = m0A * invA, muA1 = m1A * invA, muA2 = m2A * invA;
    const float cA00 = s00A * invA - muA0 * muA0;
    const float cA01 = s01A * invA - muA0 * muA1;
    const float cA02 = s02A * invA - muA0 * muA2;
    const float cA11 = s11A * invA - muA1 * muA1;
    const float cA12 = s12A * invA - muA1 * muA2;
    const float cA22 = s22A * invA - muA2 * muA2;

    const float invB = 1.f / (wsB + EPS);
    const float muB0 = m0B * invB, muB1 = m1B * invB, muB2 = m2B * invB;
    const float cB00 = s00B * invB - muB0 * muB0;
    const float cB01 = s01B * invB - muB0 * muB1;
    const float cB02 = s02B * invB - muB0 * muB2;
    const float cB11 = s11B * invB - muB1 * muB1;
    const float cB12 = s12B * invB - muB1 * muB2;
    const float cB22 = s22B * invB - muB2 * muB2;

    // ---- Phase 3: two 8-vertex chunks, staged + coalesced NT writeback ----
    float* s_out = (float*)s_out4;
    #pragma unroll
    for (int c = 0; c < 2; ++c) {
        if ((vloc >> 3) == c) {
            const int vl = vloc & 7;
            // f = 2fl and 2fl+1: 18 consecutive cov floats, 6 consecutive means
            float* so = s_out + vl * OUT_PER_V + (2 * fl) * 9;
            so[0]  = cA00; so[1]  = cA01; so[2]  = cA02;
            so[3]  = cA01; so[4]  = cA11; so[5]  = cA12;
            so[6]  = cA02; so[7]  = cA12; so[8]  = cA22;
            so[9]  = cB00; so[10] = cB01; so[11] = cB02;
            so[12] = cB01; so[13] = cB11; so[14] = cB12;
            so[15] = cB02; so[16] = cB12; so[17] = cB22;
            float* sm = s_out + vl * OUT_PER_V + F * 9 + (2 * fl) * 3;
            sm[0] = muA0; sm[1] = muA1; sm[2] = muA2;
            sm[3] = muB0; sm[4] = muB1; sm[5] = muB2;
        }
        __syncthreads();

        const int vb    = vbase + c * 8;
        const int rem_v = V - vb;                       // may be <= 0 on tail
        const int lim   = (rem_v >= 8 ? 8 : (rem_v > 0 ? rem_v : 0)) * 96;
        floatx4* o4 = (floatx4*)(out + (size_t)vb * OUT_PER_V);
        #pragma unroll
        for (int g = tid; g < OUT_F4; g += 256) {
            if (g < lim) {
                __builtin_nontemporal_store(s_out4[g], o4 + g);  // contiguous b128
            }
        }
        __syncthreads();  // stage reuse by next chunk
    }
}

// ---- Fallback: R4 structure, f32 features (95 us known-good) ----
constexpr int VPB8 = 8;
constexpr int PAIRS8 = VPB8 * K;              // 320
constexpr int OUT_F4_8 = VPB8 * OUT_PER_V / 4;// 768

__global__ __launch_bounds__(256) void neighcov_f32(
    const float* __restrict__ coords, const float* __restrict__ distsq,
    const float* __restrict__ features, const int* __restrict__ nidx,
    float* __restrict__ out, int V)
{
    __shared__ float4  s_wxyz[PAIRS8];
    __shared__ int     s_joff[PAIRS8];
    __shared__ floatx4 s_out4[OUT_F4_8];

    const int tid   = threadIdx.x;
    const int vbase = blockIdx.x * VPB8;
    const long long total_pairs = (long long)V * K;

    #pragma unroll
    for (int p = tid; p < PAIRS8; p += 256) {
        const long long gp = (long long)vbase * K + p;
        int idx = -1; float d = 0.f;
        if (gp < total_pairs) {
            idx = __builtin_nontemporal_load(nidx + gp);
            d   = __builtin_nontemporal_load(distsq + gp);
        }
        const bool valid = (idx >= 0);
        const int j = valid ? idx : 0;
        const float w = valid ? __expf(-DIST_SCALE * d) : 0.f;
        s_wxyz[p] = make_float4(w, coords[(size_t)j * 3 + 0],
                                coords[(size_t)j * 3 + 1], coords[(size_t)j * 3 + 2]);
        s_joff[p] = j * F;
    }
    __syncthreads();

    const int f = tid & (F - 1), vloc = tid >> 5;
    const float4* wp = &s_wxyz[vloc * K];
    const int*    jp = &s_joff[vloc * K];

    float wsum = 0.f, m0 = 0.f, m1 = 0.f, m2 = 0.f;
    float s00 = 0.f, s01 = 0.f, s02 = 0.f, s11 = 0.f, s12 = 0.f, s22 = 0.f;
    #pragma unroll 8
    for (int k = 0; k < K; ++k) {
        const float4 q = wp[k];
        const float feat = features[jp[k] + f];
        const float fw = q.x * feat;
        const float x = q.y, y = q.z, z = q.w;
        const float fx = fw * x, fy = fw * y, fz = fw * z;
        wsum += fw; m0 += fx; m1 += fy; m2 += fz;
        s00 += fx * x; s01 += fx * y; s02 += fx * z;
        s11 += fy * y; s12 += fy * z; s22 += fz * z;
    }
    const float inv = 1.f / (wsum + EPS);
    const float mu0 = m0 * inv, mu1 = m1 * inv, mu2 = m2 * inv;
    float* s_out = (float*)s_out4;
    float* so = s_out + vloc * OUT_PER_V + f * 9;
    so[0] = s00 * inv - mu0 * mu0; so[1] = s01 * inv - mu0 * mu1;
    so[2] = s02 * inv - mu0 * mu2; so[3] = so[1];
    so[4] = s11 * inv - mu1 * mu1; so[5] = s12 * inv - mu1 * mu2;
    so[6] = so[2]; so[7] = so[5]; so[8] = s22 * inv - mu2 * mu2;
    float* sm = s_out + vloc * OUT_PER_V + F * 9 + f * 3;
    sm[0] = mu0; sm[1] = mu1; sm[2] = mu2;
    __syncthreads();

    const int rem_v = V - vbase;
    const int lim_f4 = (rem_v >= VPB8) ? OUT_F4_8 : rem_v * (OUT_PER_V / 4);
    floatx4* o4 = (floatx4*)(out + (size_t)vbase * OUT_PER_V);
    #pragma unroll
    for (int g = tid; g < OUT_F4_8; g += 256)
        if (g < lim_f4) __builtin_nontemporal_store(s_out4[g], o4 + g);
}

extern "C" void kernel_launch(void* const* d_in, const int* in_sizes, int n_in,
                              void* d_out, int out_size, void* d_ws, size_t ws_size,
                              hipStream_t stream) {
    const float* coords   = (const float*)d_in[0];
    const float* distsq   = (const float*)d_in[1];
    const float* features = (const float*)d_in[2];
    const int*   nidx     = (const int*)d_in[3];
    float* out = (float*)d_out;

    const int V = in_sizes[0] / C;            // coordinates is V x 3

    const size_t need = (size_t)V * F * sizeof(_Float16);
    const int nelem = V * F;
    if (ws_size >= need && (nelem & 7) == 0) {
        _Float16* feat16 = (_Float16*)d_ws;
        const int n8 = nelem / 8;
        cvt_kernel<<<(n8 + 255) / 256, 256, 0, stream>>>(features, feat16, n8);
        const int blocks = (V + VPB - 1) / VPB;
        neighcov_f16x2<<<blocks, 256, 0, stream>>>(
            coords, distsq, feat16, nidx, out, V);
    } else {
        const int blocks = (V + VPB8 - 1) / VPB8;
        neighcov_f32<<<blocks, 256, 0, stream>>>(
            coords, distsq, features, nidx, out, V);
    }
}